// Round 1
// baseline (330.364 us; speedup 1.0000x reference)
//
#include <hip/hip_runtime.h>
#include <cstddef>

#define NB 8
#define TQ 2048
#define TV 2048
#define DD 128
#define KVT 32

typedef _Float16 f16x8 __attribute__((ext_vector_type(8)));
typedef float f32x4 __attribute__((ext_vector_type(4)));

__device__ __forceinline__ f16x8 load_cvt8(const float* __restrict__ p) {
  float4 a = *reinterpret_cast<const float4*>(p);
  float4 b = *reinterpret_cast<const float4*>(p + 4);
  f16x8 h;
  h[0] = (_Float16)a.x; h[1] = (_Float16)a.y;
  h[2] = (_Float16)a.z; h[3] = (_Float16)a.w;
  h[4] = (_Float16)b.x; h[5] = (_Float16)b.y;
  h[6] = (_Float16)b.z; h[7] = (_Float16)b.w;
  return h;
}

// One wave (64 threads) per block; each wave owns 16 Q rows and loops all KV.
// mfma_f32_16x16x32_f16 layouts (per guide, m89-verified C/D):
//   A frag: row = lane&15, k = (lane>>4)*8 + j  (8 contiguous)
//   B frag: col = lane&15, k = (lane>>4)*8 + j  (8 contiguous)
//   C/D   : col = lane&15, row = (lane>>4)*4 + reg
__global__ __launch_bounds__(64, 4) void attn_f32_kernel(
    const float* __restrict__ q, const float* __restrict__ v,
    const float* __restrict__ k, const float* __restrict__ scale_p,
    const int* __restrict__ mask_q, const int* __restrict__ mask_v,
    float* __restrict__ out)
{
  // P tile 16x32 f16, row stride 40 halves (80B -> 16B-aligned frag reads)
  __shared__ __align__(16) _Float16 plds[16 * 40];

  const int lane = threadIdx.x & 63;
  const int l15 = lane & 15;
  const int lg  = lane >> 4;

  const int qblocks = TQ / 16;  // 128 per batch
  const int b  = blockIdx.x / qblocks;
  const int qb = blockIdx.x % qblocks;
  const int qbase = qb * 16;

  const float scale = scale_p[0];

  const float* qp    = q + ((size_t)b * TQ + qbase) * DD;
  const float* kbase = k + (size_t)b * TV * DD;
  const float* vbase = v + (size_t)b * TV * DD;
  const int*   mvb   = mask_v + b * TV;

  // Preload Q fragments (16 rows x 128 d, f32 -> f16)
  f16x8 qf[4];
#pragma unroll
  for (int kc = 0; kc < 4; ++kc)
    qf[kc] = load_cvt8(qp + (size_t)l15 * DD + kc * 32 + lg * 8);

  f32x4 acc[8];
#pragma unroll
  for (int i = 0; i < 8; ++i) acc[i] = (f32x4){0.f, 0.f, 0.f, 0.f};
  float m[4], lsum[4];
#pragma unroll
  for (int r = 0; r < 4; ++r) { m[r] = -3.0e38f; lsum[r] = 0.f; }

  for (int kt = 0; kt < TV; kt += KVT) {
    // ---- S = scale * Q K^T (+ additive value-mask) ----
    f32x4 s0 = {0.f, 0.f, 0.f, 0.f}, s1 = {0.f, 0.f, 0.f, 0.f};
#pragma unroll
    for (int kc = 0; kc < 4; ++kc) {
      f16x8 kf0 = load_cvt8(kbase + (size_t)(kt + l15) * DD + kc * 32 + lg * 8);
      s0 = __builtin_amdgcn_mfma_f32_16x16x32_f16(qf[kc], kf0, s0, 0, 0, 0);
      f16x8 kf1 = load_cvt8(kbase + (size_t)(kt + 16 + l15) * DD + kc * 32 + lg * 8);
      s1 = __builtin_amdgcn_mfma_f32_16x16x32_f16(qf[kc], kf1, s1, 0, 0, 0);
    }
    const float a0 = (mvb[kt + l15]      != 0) ? 0.f : -1e9f;
    const float a1 = (mvb[kt + 16 + l15] != 0) ? 0.f : -1e9f;

    float pm[4];
#pragma unroll
    for (int r = 0; r < 4; ++r) {
      s0[r] = s0[r] * scale + a0;
      s1[r] = s1[r] * scale + a1;
      pm[r] = fmaxf(s0[r], s1[r]);
    }
    // row-max across the 16 lanes holding this row's cols
#pragma unroll
    for (int off = 1; off < 16; off <<= 1)
#pragma unroll
      for (int r = 0; r < 4; ++r)
        pm[r] = fmaxf(pm[r], __shfl_xor(pm[r], off, 64));

    float alpha[4], ps[4];
#pragma unroll
    for (int r = 0; r < 4; ++r) {
      float mn = fmaxf(m[r], pm[r]);
      alpha[r] = __expf(m[r] - mn);
      m[r] = mn;
      float p0 = __expf(s0[r] - mn);
      float p1 = __expf(s1[r] - mn);
      ps[r] = p0 + p1;
      int row = lg * 4 + r;
      plds[row * 40 + l15]      = (_Float16)p0;
      plds[row * 40 + 16 + l15] = (_Float16)p1;
    }
#pragma unroll
    for (int off = 1; off < 16; off <<= 1)
#pragma unroll
      for (int r = 0; r < 4; ++r)
        ps[r] += __shfl_xor(ps[r], off, 64);
#pragma unroll
    for (int r = 0; r < 4; ++r) {
      lsum[r] = lsum[r] * alpha[r] + ps[r];
#pragma unroll
      for (int ct = 0; ct < 8; ++ct) acc[ct][r] *= alpha[r];
    }

    // ---- O += P V ----  (A-frag of P via LDS transpose; wave-synchronous)
    f16x8 pa = *reinterpret_cast<const f16x8*>(&plds[l15 * 40 + lg * 8]);
#pragma unroll
    for (int ct = 0; ct < 8; ++ct) {
      const float* vp = vbase + (size_t)(kt + lg * 8) * DD + ct * 16 + l15;
      f16x8 vf;
#pragma unroll
      for (int j = 0; j < 8; ++j) vf[j] = (_Float16)vp[(size_t)j * DD];
      acc[ct] = __builtin_amdgcn_mfma_f32_16x16x32_f16(pa, vf, acc[ct], 0, 0, 0);
    }
  }

  // ---- epilogue: /lsum, query-mask, store ----
  const int* mqb = mask_q + b * TQ;
#pragma unroll
  for (int r = 0; r < 4; ++r) {
    int row = lg * 4 + r;
    int qr = qbase + row;
    float f = ((mqb[qr] != 0) ? 1.f : 0.f) / lsum[r];
    float* orow = out + ((size_t)b * TQ + qr) * DD;
#pragma unroll
    for (int ct = 0; ct < 8; ++ct) orow[ct * 16 + l15] = acc[ct][r] * f;
  }
}

extern "C" void kernel_launch(void* const* d_in, const int* in_sizes, int n_in,
                              void* d_out, int out_size, void* d_ws, size_t ws_size,
                              hipStream_t stream) {
  const float* q       = (const float*)d_in[0];
  const float* v       = (const float*)d_in[1];
  const float* k       = (const float*)d_in[2];
  const float* scale   = (const float*)d_in[3];
  const int*   mask_q  = (const int*)d_in[4];
  const int*   mask_v  = (const int*)d_in[5];
  float* out = (float*)d_out;

  dim3 grid(NB * (TQ / 16));
  dim3 block(64);
  hipLaunchKernelGGL(attn_f32_kernel, grid, block, 0, stream,
                     q, v, k, scale, mask_q, mask_v, out);
}

// Round 2
// 76.735 us; speedup vs baseline: 4.3053x; 4.3053x over previous
//
#include <hip/hip_runtime.h>
#include <cstddef>

#define NB 8
#define TQ 2048
#define TV 2048
#define DD 128
#define KVT 32
#define NW 4          // waves per block = KV split factor
#define CHUNK (TV / NW)

typedef _Float16 f16x8 __attribute__((ext_vector_type(8)));
typedef _Float16 f16x4 __attribute__((ext_vector_type(4)));
typedef float f32x4 __attribute__((ext_vector_type(4)));

// ---------------- prepass: q,k -> f16 ; v -> f16 transposed [B][D][TV] ---------
__global__ __launch_bounds__(256) void prepass_kernel(
    const float* __restrict__ q, const float* __restrict__ k,
    const float* __restrict__ v,
    _Float16* __restrict__ qh, _Float16* __restrict__ kh, _Float16* __restrict__ vt)
{
  __shared__ _Float16 tlds[32 * 34];
  const int tid = threadIdx.x;
  const int bid = blockIdx.x;
  if (bid < 2048) {                       // cast Q
    size_t idx = (size_t)bid * 256 + tid;
    float4 x = ((const float4*)q)[idx];
    f16x4 h; h[0] = (_Float16)x.x; h[1] = (_Float16)x.y; h[2] = (_Float16)x.z; h[3] = (_Float16)x.w;
    ((f16x4*)qh)[idx] = h;
  } else if (bid < 4096) {                // cast K
    size_t idx = (size_t)(bid - 2048) * 256 + tid;
    float4 x = ((const float4*)k)[idx];
    f16x4 h; h[0] = (_Float16)x.x; h[1] = (_Float16)x.y; h[2] = (_Float16)x.z; h[3] = (_Float16)x.w;
    ((f16x4*)kh)[idx] = h;
  } else {                                // transpose V tile 32x32
    int tb = bid - 4096;                  // 8 b * 64 kt * 4 dt
    int b = tb >> 8, rem = tb & 255;
    int kt = rem >> 2, dt = rem & 3;
    int r = tid >> 3, c0 = (tid & 7) * 4;
    float4 x = *(const float4*)&v[((size_t)b * TV + kt * 32 + r) * DD + dt * 32 + c0];
    tlds[(c0 + 0) * 34 + r] = (_Float16)x.x;
    tlds[(c0 + 1) * 34 + r] = (_Float16)x.y;
    tlds[(c0 + 2) * 34 + r] = (_Float16)x.z;
    tlds[(c0 + 3) * 34 + r] = (_Float16)x.w;
    __syncthreads();
    int dl = tid >> 3, k0 = (tid & 7) * 4;
    f16x4 h;
#pragma unroll
    for (int i = 0; i < 4; ++i) h[i] = tlds[dl * 34 + k0 + i];
    size_t eidx = ((size_t)b * DD + dt * 32 + dl) * TV + kt * 32 + k0;
    *(f16x4*)&vt[eidx] = h;
  }
}

// ---------------- main: 4 waves/block, 32 Q rows shared, KV split x4 -----------
__global__ __launch_bounds__(256, 2) void attn_main(
    const _Float16* __restrict__ qh, const _Float16* __restrict__ kh,
    const _Float16* __restrict__ vt, const float* __restrict__ scale_p,
    const int* __restrict__ mask_q, const int* __restrict__ mask_v,
    float* __restrict__ out)
{
  __shared__ __align__(16) unsigned char ldsraw[66560];
  float* osh = (float*)ldsraw;                   // [4][32][128] f32
  float* msh = (float*)(ldsraw + 65536);         // [4][32]
  float* lsh = (float*)(ldsraw + 66048);         // [4][32]

  const int tid = threadIdx.x;
  const int w = tid >> 6;
  const int lane = tid & 63;
  const int l15 = lane & 15, lg = lane >> 4;

  const int b = blockIdx.x & 7;
  const int qg = blockIdx.x >> 3;        // 0..63
  const int qbase = qg * 32;
  const int kv0 = w * CHUNK;

  const float scale = scale_p[0];
  const _Float16* qhb = qh + ((size_t)b * TQ + qbase) * DD;
  const _Float16* khb = kh + (size_t)b * TV * DD;
  const _Float16* vtb = vt + (size_t)b * DD * TV;
  const int* mvb = mask_v + b * TV;

  // per-wave P-transpose scratch: [2 rb][16][40] f16, lives inside osh region
  // (dead before osh is written; barrier separates the two uses)
  _Float16* plds = (_Float16*)ldsraw + (size_t)w * 1280 * 2;

  f16x8 qf[2][4];
#pragma unroll
  for (int rb = 0; rb < 2; ++rb)
#pragma unroll
    for (int kc = 0; kc < 4; ++kc)
      qf[rb][kc] = *(const f16x8*)(qhb + (size_t)(rb * 16 + l15) * DD + kc * 32 + lg * 8);

  f32x4 acc[2][8];
#pragma unroll
  for (int rb = 0; rb < 2; ++rb)
#pragma unroll
    for (int ct = 0; ct < 8; ++ct) acc[rb][ct] = (f32x4){0.f, 0.f, 0.f, 0.f};
  float m[2][4], lsum[2][4];
#pragma unroll
  for (int rb = 0; rb < 2; ++rb)
#pragma unroll
    for (int r = 0; r < 4; ++r) { m[rb][r] = -3.0e38f; lsum[rb][r] = 0.f; }

  for (int t = 0; t < CHUNK / KVT; ++t) {
    const int kt = kv0 + t * KVT;
    f32x4 s[2][2];
    s[0][0] = (f32x4){0,0,0,0}; s[0][1] = (f32x4){0,0,0,0};
    s[1][0] = (f32x4){0,0,0,0}; s[1][1] = (f32x4){0,0,0,0};
#pragma unroll
    for (int kc = 0; kc < 4; ++kc) {
      f16x8 kf0 = *(const f16x8*)(khb + (size_t)(kt + l15) * DD + kc * 32 + lg * 8);
      f16x8 kf1 = *(const f16x8*)(khb + (size_t)(kt + 16 + l15) * DD + kc * 32 + lg * 8);
      s[0][0] = __builtin_amdgcn_mfma_f32_16x16x32_f16(qf[0][kc], kf0, s[0][0], 0, 0, 0);
      s[1][0] = __builtin_amdgcn_mfma_f32_16x16x32_f16(qf[1][kc], kf0, s[1][0], 0, 0, 0);
      s[0][1] = __builtin_amdgcn_mfma_f32_16x16x32_f16(qf[0][kc], kf1, s[0][1], 0, 0, 0);
      s[1][1] = __builtin_amdgcn_mfma_f32_16x16x32_f16(qf[1][kc], kf1, s[1][1], 0, 0, 0);
    }
    const float a0 = (mvb[kt + l15]      != 0) ? 0.f : -1e9f;
    const float a1 = (mvb[kt + 16 + l15] != 0) ? 0.f : -1e9f;

    f16x8 pa[2];
#pragma unroll
    for (int rb = 0; rb < 2; ++rb) {
      float pm[4];
#pragma unroll
      for (int r = 0; r < 4; ++r) {
        s[rb][0][r] = s[rb][0][r] * scale + a0;
        s[rb][1][r] = s[rb][1][r] * scale + a1;
        pm[r] = fmaxf(s[rb][0][r], s[rb][1][r]);
      }
#pragma unroll
      for (int off = 1; off < 16; off <<= 1)
#pragma unroll
        for (int r = 0; r < 4; ++r)
          pm[r] = fmaxf(pm[r], __shfl_xor(pm[r], off, 64));

      float al[4], ps[4];
      _Float16* pl = plds + rb * 1280 / 2;   // wait: 1280 f16 per rb
#pragma unroll
      for (int r = 0; r < 4; ++r) {
        float mn = fmaxf(m[rb][r], pm[r]);
        al[r] = __expf(m[rb][r] - mn);
        m[rb][r] = mn;
        float p0 = __expf(s[rb][0][r] - mn);
        float p1 = __expf(s[rb][1][r] - mn);
        ps[r] = p0 + p1;
        int row = lg * 4 + r;
        pl[row * 40 + l15]      = (_Float16)p0;
        pl[row * 40 + 16 + l15] = (_Float16)p1;
      }
#pragma unroll
      for (int off = 1; off < 16; off <<= 1)
#pragma unroll
        for (int r = 0; r < 4; ++r)
          ps[r] += __shfl_xor(ps[r], off, 64);
      f32x4 alv;
#pragma unroll
      for (int r = 0; r < 4; ++r) {
        lsum[rb][r] = lsum[rb][r] * al[r] + ps[r];
        alv[r] = al[r];
      }
#pragma unroll
      for (int ct = 0; ct < 8; ++ct) acc[rb][ct] *= alv;
      pa[rb] = *(const f16x8*)(pl + l15 * 40 + lg * 8);
    }

#pragma unroll
    for (int ct = 0; ct < 8; ++ct) {
      f16x8 vf = *(const f16x8*)(vtb + (size_t)(ct * 16 + l15) * TV + kt + lg * 8);
      acc[0][ct] = __builtin_amdgcn_mfma_f32_16x16x32_f16(pa[0], vf, acc[0][ct], 0, 0, 0);
      acc[1][ct] = __builtin_amdgcn_mfma_f32_16x16x32_f16(pa[1], vf, acc[1][ct], 0, 0, 0);
    }
  }

  __syncthreads();   // all waves done with hot loop (plds now dead)

#pragma unroll
  for (int rb = 0; rb < 2; ++rb) {
#pragma unroll
    for (int ct = 0; ct < 8; ++ct)
#pragma unroll
      for (int r = 0; r < 4; ++r)
        osh[(size_t)(w * 32 + rb * 16 + lg * 4 + r) * 128 + ct * 16 + l15] = acc[rb][ct][r];
    if (l15 == 0)
#pragma unroll
      for (int r = 0; r < 4; ++r) {
        msh[w * 32 + rb * 16 + lg * 4 + r] = m[rb][r];
        lsh[w * 32 + rb * 16 + lg * 4 + r] = lsum[rb][r];
      }
  }
  __syncthreads();

  // combine 4 KV-chunk partials
  {
    const int row = tid >> 3, cg = tid & 7;
    float mm[4]; float mstar = -3.0e38f;
#pragma unroll
    for (int wv = 0; wv < 4; ++wv) { mm[wv] = msh[wv * 32 + row]; mstar = fmaxf(mstar, mm[wv]); }
    float coef[4], lstar = 0.f;
#pragma unroll
    for (int wv = 0; wv < 4; ++wv) { coef[wv] = __expf(mm[wv] - mstar); lstar += coef[wv] * lsh[wv * 32 + row]; }
    const int qr = qbase + row;
    const float f = ((mask_q[(size_t)b * TQ + qr] != 0) ? 1.f : 0.f) / lstar;
    float4* orow = (float4*)(out + ((size_t)b * TQ + qr) * DD + cg * 16);
#pragma unroll
    for (int i4 = 0; i4 < 4; ++i4) {
      float4 sv = {0.f, 0.f, 0.f, 0.f};
#pragma unroll
      for (int wv = 0; wv < 4; ++wv) {
        float4 p = *(float4*)&osh[(size_t)(wv * 32 + row) * 128 + cg * 16 + i4 * 4];
        sv.x += coef[wv] * p.x; sv.y += coef[wv] * p.y;
        sv.z += coef[wv] * p.z; sv.w += coef[wv] * p.w;
      }
      float4 o; o.x = sv.x * f; o.y = sv.y * f; o.z = sv.z * f; o.w = sv.w * f;
      orow[i4] = o;
    }
  }
}

// ---------------- fallback (round-1 kernel) if ws too small --------------------
__global__ __launch_bounds__(64, 4) void attn_f32_kernel(
    const float* __restrict__ q, const float* __restrict__ v,
    const float* __restrict__ k, const float* __restrict__ scale_p,
    const int* __restrict__ mask_q, const int* __restrict__ mask_v,
    float* __restrict__ out)
{
  __shared__ __align__(16) _Float16 plds[16 * 40];
  const int lane = threadIdx.x & 63;
  const int l15 = lane & 15, lg = lane >> 4;
  const int qblocks = TQ / 16;
  const int b = blockIdx.x / qblocks, qb = blockIdx.x % qblocks;
  const int qbase = qb * 16;
  const float scale = scale_p[0];
  const float* qp = q + ((size_t)b * TQ + qbase) * DD;
  const float* kbase = k + (size_t)b * TV * DD;
  const float* vbase = v + (size_t)b * TV * DD;
  const int* mvb = mask_v + b * TV;
  f16x8 qf[4];
#pragma unroll
  for (int kc = 0; kc < 4; ++kc) {
    float4 a = *(const float4*)(qp + (size_t)l15 * DD + kc * 32 + lg * 8);
    float4 bb = *(const float4*)(qp + (size_t)l15 * DD + kc * 32 + lg * 8 + 4);
    f16x8 h; h[0]=(_Float16)a.x;h[1]=(_Float16)a.y;h[2]=(_Float16)a.z;h[3]=(_Float16)a.w;
    h[4]=(_Float16)bb.x;h[5]=(_Float16)bb.y;h[6]=(_Float16)bb.z;h[7]=(_Float16)bb.w;
    qf[kc]=h;
  }
  f32x4 acc[8];
#pragma unroll
  for (int i = 0; i < 8; ++i) acc[i] = (f32x4){0.f,0.f,0.f,0.f};
  float m[4], lsum[4];
#pragma unroll
  for (int r = 0; r < 4; ++r) { m[r] = -3.0e38f; lsum[r] = 0.f; }
  for (int kt = 0; kt < TV; kt += KVT) {
    f32x4 s0 = {0,0,0,0}, s1 = {0,0,0,0};
#pragma unroll
    for (int kc = 0; kc < 4; ++kc) {
      const float* kp0 = kbase + (size_t)(kt + l15) * DD + kc * 32 + lg * 8;
      float4 a = *(const float4*)kp0; float4 bb = *(const float4*)(kp0 + 4);
      f16x8 kf0; kf0[0]=(_Float16)a.x;kf0[1]=(_Float16)a.y;kf0[2]=(_Float16)a.z;kf0[3]=(_Float16)a.w;
      kf0[4]=(_Float16)bb.x;kf0[5]=(_Float16)bb.y;kf0[6]=(_Float16)bb.z;kf0[7]=(_Float16)bb.w;
      s0 = __builtin_amdgcn_mfma_f32_16x16x32_f16(qf[kc], kf0, s0, 0, 0, 0);
      const float* kp1 = kbase + (size_t)(kt + 16 + l15) * DD + kc * 32 + lg * 8;
      a = *(const float4*)kp1; bb = *(const float4*)(kp1 + 4);
      f16x8 kf1; kf1[0]=(_Float16)a.x;kf1[1]=(_Float16)a.y;kf1[2]=(_Float16)a.z;kf1[3]=(_Float16)a.w;
      kf1[4]=(_Float16)bb.x;kf1[5]=(_Float16)bb.y;kf1[6]=(_Float16)bb.z;kf1[7]=(_Float16)bb.w;
      s1 = __builtin_amdgcn_mfma_f32_16x16x32_f16(qf[kc], kf1, s1, 0, 0, 0);
    }
    const float a0 = (mvb[kt + l15] != 0) ? 0.f : -1e9f;
    const float a1 = (mvb[kt + 16 + l15] != 0) ? 0.f : -1e9f;
    float pm[4];
#pragma unroll
    for (int r = 0; r < 4; ++r) {
      s0[r] = s0[r] * scale + a0; s1[r] = s1[r] * scale + a1;
      pm[r] = fmaxf(s0[r], s1[r]);
    }
#pragma unroll
    for (int off = 1; off < 16; off <<= 1)
#pragma unroll
      for (int r = 0; r < 4; ++r) pm[r] = fmaxf(pm[r], __shfl_xor(pm[r], off, 64));
    float al[4], ps[4];
#pragma unroll
    for (int r = 0; r < 4; ++r) {
      float mn = fmaxf(m[r], pm[r]);
      al[r] = __expf(m[r] - mn); m[r] = mn;
      float p0 = __expf(s0[r] - mn), p1 = __expf(s1[r] - mn);
      ps[r] = p0 + p1;
      int row = lg * 4 + r;
      plds[row * 40 + l15] = (_Float16)p0;
      plds[row * 40 + 16 + l15] = (_Float16)p1;
    }
#pragma unroll
    for (int off = 1; off < 16; off <<= 1)
#pragma unroll
      for (int r = 0; r < 4; ++r) ps[r] += __shfl_xor(ps[r], off, 64);
#pragma unroll
    for (int r = 0; r < 4; ++r) {
      lsum[r] = lsum[r] * al[r] + ps[r];
#pragma unroll
      for (int ct = 0; ct < 8; ++ct) acc[ct][r] *= al[r];
    }
    f16x8 pa = *(const f16x8*)&plds[l15 * 40 + lg * 8];
#pragma unroll
    for (int ct = 0; ct < 8; ++ct) {
      const float* vp = vbase + (size_t)(kt + lg * 8) * DD + ct * 16 + l15;
      f16x8 vf;
#pragma unroll
      for (int j = 0; j < 8; ++j) vf[j] = (_Float16)vp[(size_t)j * DD];
      acc[ct] = __builtin_amdgcn_mfma_f32_16x16x32_f16(pa, vf, acc[ct], 0, 0, 0);
    }
  }
  const int* mqb = mask_q + b * TQ;
#pragma unroll
  for (int r = 0; r < 4; ++r) {
    int row = lg * 4 + r;
    int qr = qbase + row;
    float f = ((mqb[qr] != 0) ? 1.f : 0.f) / lsum[r];
    float* orow = out + ((size_t)b * TQ + qr) * DD;
#pragma unroll
    for (int ct = 0; ct < 8; ++ct) orow[ct * 16 + l15] = acc[ct][r] * f;
  }
}

extern "C" void kernel_launch(void* const* d_in, const int* in_sizes, int n_in,
                              void* d_out, int out_size, void* d_ws, size_t ws_size,
                              hipStream_t stream) {
  const float* q      = (const float*)d_in[0];
  const float* v      = (const float*)d_in[1];
  const float* k      = (const float*)d_in[2];
  const float* scale  = (const float*)d_in[3];
  const int*   mask_q = (const int*)d_in[4];
  const int*   mask_v = (const int*)d_in[5];
  float* out = (float*)d_out;

  const size_t need = 3ull * NB * TV * DD * sizeof(_Float16);  // 12 MB
  if (ws_size >= need) {
    _Float16* qh = (_Float16*)d_ws;
    _Float16* kh = qh + (size_t)NB * TQ * DD;
    _Float16* vt = kh + (size_t)NB * TV * DD;
    hipLaunchKernelGGL(prepass_kernel, dim3(4096 + 2048), dim3(256), 0, stream,
                       q, k, v, qh, kh, vt);
    hipLaunchKernelGGL(attn_main, dim3(NB * (TQ / 32)), dim3(256), 0, stream,
                       qh, kh, vt, scale, mask_q, mask_v, out);
  } else {
    hipLaunchKernelGGL(attn_f32_kernel, dim3(NB * (TQ / 16)), dim3(64), 0, stream,
                       q, v, k, scale, mask_q, mask_v, out);
  }
}